// Round 1
// baseline (143.256 us; speedup 1.0000x reference)
//
#include <hip/hip_runtime.h>

#define POOL 7
#define NUM_ROIS 512
#define IMG_H 64
#define IMG_W 64
#define IMG_C 1024

// One block per (roi, pool_i, pool_j). 256 threads x float4 = 1024 channels.
// The 4 bilinear source pixel addresses are block-uniform; channel accesses
// are fully coalesced (256 lanes x 16B = 4KB contiguous per pixel).
__global__ __launch_bounds__(256) void roi_pool_kernel(
    const float* __restrict__ img,
    const int*   __restrict__ rois,
    float*       __restrict__ out)
{
    const int b  = blockIdx.x;              // r*49 + i*7 + j
    const int r  = b / 49;
    const int ij = b - r * 49;
    const int i  = ij / 7;
    const int j  = ij - i * 7;

    const int4 roi = reinterpret_cast<const int4*>(rois)[r];
    const int x = roi.x, y = roi.y, w = roi.z, h = roi.w;

    // Match reference fp32 arithmetic exactly.
    const float sy = (float)i * ((float)h / 7.0f);
    const float sx = (float)j * ((float)w / 7.0f);
    const int y0 = (int)floorf(sy);
    const int x0 = (int)floorf(sx);
    const float fy = sy - (float)y0;
    const float fx = sx - (float)x0;
    const int y1 = min(y0 + 1, h - 1);
    const int x1 = min(x0 + 1, w - 1);
    const int gy0 = y + y0, gy1 = y + y1;
    const int gx0 = x + x0, gx1 = x + x1;

    const int c = threadIdx.x * 4;

    const float4 v00 = *reinterpret_cast<const float4*>(&img[((size_t)gy0 * IMG_W + gx0) * IMG_C + c]);
    const float4 v01 = *reinterpret_cast<const float4*>(&img[((size_t)gy0 * IMG_W + gx1) * IMG_C + c]);
    const float4 v10 = *reinterpret_cast<const float4*>(&img[((size_t)gy1 * IMG_W + gx0) * IMG_C + c]);
    const float4 v11 = *reinterpret_cast<const float4*>(&img[((size_t)gy1 * IMG_W + gx1) * IMG_C + c]);

    float4 res;
    {
        const float t0 = v00.x + (v01.x - v00.x) * fx;
        const float b0 = v10.x + (v11.x - v10.x) * fx;
        res.x = t0 + (b0 - t0) * fy;
    }
    {
        const float t0 = v00.y + (v01.y - v00.y) * fx;
        const float b0 = v10.y + (v11.y - v10.y) * fx;
        res.y = t0 + (b0 - t0) * fy;
    }
    {
        const float t0 = v00.z + (v01.z - v00.z) * fx;
        const float b0 = v10.z + (v11.z - v10.z) * fx;
        res.z = t0 + (b0 - t0) * fy;
    }
    {
        const float t0 = v00.w + (v01.w - v00.w) * fx;
        const float b0 = v10.w + (v11.w - v10.w) * fx;
        res.w = t0 + (b0 - t0) * fy;
    }

    reinterpret_cast<float4*>(out)[(size_t)b * (IMG_C / 4) + threadIdx.x] = res;
}

extern "C" void kernel_launch(void* const* d_in, const int* in_sizes, int n_in,
                              void* d_out, int out_size, void* d_ws, size_t ws_size,
                              hipStream_t stream) {
    const float* img  = (const float*)d_in[0];
    const int*   rois = (const int*)d_in[1];
    float*       out  = (float*)d_out;

    const int grid = NUM_ROIS * POOL * POOL;   // 25088 blocks
    roi_pool_kernel<<<grid, 256, 0, stream>>>(img, rois, out);
}

// Round 3
// 143.143 us; speedup vs baseline: 1.0008x; 1.0008x over previous
//
#include <hip/hip_runtime.h>

#define POOL 7
#define NUM_ROIS 512
#define IMG_W 64
#define IMG_C 1024
#define NXCD 8

typedef float vfloat4 __attribute__((ext_vector_type(4)));

// One block per (roi, pool_row). 256 threads x float4 = 1024 channels.
// All 7 cells of the row are computed by the block: 28 independent float4
// loads per thread give deep MLP; the two source image rows are reused
// across cells through L1/L2. XCD-aware swizzle clusters a ROI's blocks
// (and 64 consecutive ROIs) on one XCD's L2. Output stores are
// non-temporal: 103 MB streaming writes should not evict img from L2.
__global__ __launch_bounds__(256) void roi_pool_kernel(
    const float* __restrict__ img,
    const int*   __restrict__ rois,
    float*       __restrict__ out)
{
    // --- XCD-aware bijective swizzle (grid = 3584, 3584 % 8 == 0) ---
    const int nwg = NUM_ROIS * POOL;      // 3584
    const int cpx = nwg / NXCD;           // 448 blocks (= 64 ROIs) per XCD
    int b = blockIdx.x;
    b = (b % NXCD) * cpx + b / NXCD;

    const int r = b / POOL;               // roi index
    const int i = b - r * POOL;           // pool row

    const int4 roi = reinterpret_cast<const int4*>(rois)[r];
    const int x = roi.x, y = roi.y, w = roi.z, h = roi.w;

    // Match reference fp32 arithmetic exactly.
    const float hf = (float)h / 7.0f;
    const float wf = (float)w / 7.0f;
    const float sy = (float)i * hf;
    const int   y0 = (int)floorf(sy);
    const float fy = sy - (float)y0;
    const int   y1 = min(y0 + 1, h - 1);

    const size_t row0 = (size_t)(y + y0) * IMG_W;
    const size_t row1 = (size_t)(y + y1) * IMG_W;

    const int c = threadIdx.x * 4;        // channel offset (float index)

    vfloat4 v00[POOL], v01[POOL], v10[POOL], v11[POOL];
    float   fx[POOL];

#pragma unroll
    for (int j = 0; j < POOL; ++j) {
        const float sx = (float)j * wf;
        const int   x0 = (int)floorf(sx);
        fx[j] = sx - (float)x0;
        const int   x1 = min(x0 + 1, w - 1);
        const int gx0 = x + x0, gx1 = x + x1;
        v00[j] = *reinterpret_cast<const vfloat4*>(&img[(row0 + gx0) * IMG_C + c]);
        v01[j] = *reinterpret_cast<const vfloat4*>(&img[(row0 + gx1) * IMG_C + c]);
        v10[j] = *reinterpret_cast<const vfloat4*>(&img[(row1 + gx0) * IMG_C + c]);
        v11[j] = *reinterpret_cast<const vfloat4*>(&img[(row1 + gx1) * IMG_C + c]);
    }

    // out[r][i][j][c] : flat vfloat4 index = ((r*7 + i)*7 + j)*256 + tid
    vfloat4* outv = reinterpret_cast<vfloat4*>(out)
                  + ((size_t)b * POOL) * (IMG_C / 4) + threadIdx.x;

#pragma unroll
    for (int j = 0; j < POOL; ++j) {
        const vfloat4 a = v00[j], bv = v01[j], cv = v10[j], d = v11[j];
        const vfloat4 t = a + (bv - a) * fx[j];
        const vfloat4 u = cv + (d - cv) * fx[j];
        const vfloat4 res = t + (u - t) * fy;
        __builtin_nontemporal_store(res, &outv[(size_t)j * (IMG_C / 4)]);
    }
}

extern "C" void kernel_launch(void* const* d_in, const int* in_sizes, int n_in,
                              void* d_out, int out_size, void* d_ws, size_t ws_size,
                              hipStream_t stream) {
    const float* img  = (const float*)d_in[0];
    const int*   rois = (const int*)d_in[1];
    float*       out  = (float*)d_out;

    const int grid = NUM_ROIS * POOL;     // 3584 blocks, one per (roi, row)
    roi_pool_kernel<<<grid, 256, 0, stream>>>(img, rois, out);
}